// Round 1
// baseline (218.263 us; speedup 1.0000x reference)
//
#include <hip/hip_runtime.h>
#include <hip/hip_fp16.h>

typedef _Float16 f16;
typedef __attribute__((ext_vector_type(8)))  f16   f16x8;
typedef __attribute__((ext_vector_type(16))) float f32x16;
typedef __attribute__((ext_vector_type(4)))  float f32x4;
typedef __attribute__((ext_vector_type(2)))  unsigned int u32x2;
typedef unsigned int uint;
typedef unsigned short ushort;

#define MFMA16 __builtin_amdgcn_mfma_f32_32x32x16_f16

#define SCALE_Q 0.17677669529663687f   // 1/sqrt(32)

// ---------------- LDS layout (bytes) ----------------
#define XN_ROW   264                    // fp16 elems per row (256 + 8 pad) -> 528B = 132 dw = 4 mod 32
#define XN_BYTES (64 * XN_ROW * 2)      // 33792 ; reused later as attention-output tile
#define Q_OFF    XN_BYTES
#define QK_ROW   40                     // 32 + 8 pad -> 80B = 20 dw
#define QK_HEAD  (64 * QK_ROW * 2)      // 5120
#define Q_BYTES  (8 * QK_HEAD)          // 40960
#define K_OFF    (Q_OFF + Q_BYTES)
#define K_BYTES  Q_BYTES
#define VT_OFF   (K_OFF + K_BYTES)
#define VT_ROW   72                     // 64 + 8 pad -> 144B = 36 dw = 4 mod 32
#define VT_HEAD  (32 * VT_ROW * 2)      // 4608
#define VT_BYTES (8 * VT_HEAD)          // 36864
#define LDS_TOTAL (VT_OFF + VT_BYTES)   // 152576 <= 163840

#define Z16 {0.f,0.f,0.f,0.f,0.f,0.f,0.f,0.f,0.f,0.f,0.f,0.f,0.f,0.f,0.f,0.f}

__device__ __forceinline__ ushort f2h_bits(float f) {
    return __builtin_bit_cast(ushort, (f16)f);
}
__device__ __forceinline__ uint pk2(float a, float b) {
    return (uint)f2h_bits(a) | ((uint)f2h_bits(b) << 16);
}

// ---------------- prep: weight fp16 conversion + bias gather into fragment order ----------------
__global__ void lwa_prep(const float* __restrict__ qkvw, const float* __restrict__ projw,
                         const float* __restrict__ table, const int* __restrict__ ridx,
                         ushort* __restrict__ wq, ushort* __restrict__ wp, float* __restrict__ biasr)
{
    int i = blockIdx.x * 256 + threadIdx.x;
    if (i < 196608) {                       // qkv_w (768x256), fold q-scale into rows e<256
        float v = qkvw[i];
        if (i < 65536) v *= SCALE_Q;
        wq[i] = f2h_bits(v);
    } else if (i < 262144) {                // proj_w (256x256)
        int j = i - 196608;
        wp[j] = f2h_bits(projw[j]);
    } else {                                // bias -> [h][mt][nt][lane][reg] f32 (32768)
        int j = i - 262144;
        int reg  = j & 15;
        int lane = (j >> 4) & 63;
        int nt   = (j >> 10) & 1;
        int mt   = (j >> 11) & 1;
        int h    = j >> 12;
        int qrow = nt * 32 + (lane & 31);                               // C-frag col
        int kv   = mt * 32 + (reg & 3) + 8 * (reg >> 2) + 4 * (lane >> 5); // C-frag row
        biasr[j] = table[ridx[qrow * 64 + kv] * 8 + h];
    }
}

// ---------------- main fused kernel: one block per window ----------------
__global__ __launch_bounds__(512, 2) void lwa_main(
    const float* __restrict__ x, const float* __restrict__ nz,
    const float* __restrict__ gamma, const float* __restrict__ beta,
    const ushort* __restrict__ wq, const ushort* __restrict__ wp,
    const float* __restrict__ biasr, const float* __restrict__ projb,
    float* __restrict__ out)
{
    extern __shared__ char smem[];
    const int tid  = threadIdx.x;
    const int wid  = tid >> 6;       // wave id == head id
    const int lane = tid & 63;
    const int l31  = lane & 31;
    const int h5   = lane >> 5;
    const int w    = blockIdx.x;     // window 0..2047
    const int bidx = w >> 8;         // batch (N = 256)
    const int kb   = h5 * 8;

    // ---- Phase 1: xw = x*noise, LayerNorm over 256, write xn fp16 to LDS ----
    {
        const int p   = tid >> 3;    // row 0..63
        const int sub = tid & 7;     // 8 threads per row
        const float* xrow = x  + (size_t)w * 16384 + p * 256;
        const float* nrow = nz + (size_t)bidx * 16384 + p * 256;
        f32x4 v[8];
        float s = 0.f, ss = 0.f;
#pragma unroll
        for (int i = 0; i < 8; ++i) {
            const int c4 = sub + 8 * i;
            f32x4 xv = *(const f32x4*)(xrow + 4 * c4);
            f32x4 nv = *(const f32x4*)(nrow + 4 * c4);
            f32x4 t = xv * nv;
            v[i] = t;
            s  += t[0] + t[1] + t[2] + t[3];
            ss += t[0]*t[0] + t[1]*t[1] + t[2]*t[2] + t[3]*t[3];
        }
#pragma unroll
        for (int m = 1; m < 8; m <<= 1) { s += __shfl_xor(s, m, 64); ss += __shfl_xor(ss, m, 64); }
        const float mu = s * (1.f / 256.f);
        const float rs = rsqrtf(fmaxf(ss * (1.f / 256.f) - mu * mu, 0.f) + 1e-5f);
        char* xnrow = smem + (size_t)p * (XN_ROW * 2);
#pragma unroll
        for (int i = 0; i < 8; ++i) {
            const int c4 = sub + 8 * i;
            f32x4 g  = *(const f32x4*)(gamma + 4 * c4);
            f32x4 bb = *(const f32x4*)(beta  + 4 * c4);
            f32x4 t  = v[i];
            u32x2 pkv;
            pkv[0] = pk2((t[0]-mu)*rs*g[0] + bb[0], (t[1]-mu)*rs*g[1] + bb[1]);
            pkv[1] = pk2((t[2]-mu)*rs*g[2] + bb[2], (t[3]-mu)*rs*g[3] + bb[3]);
            *(u32x2*)(xnrow + c4 * 8) = pkv;
        }
    }
    __syncthreads();

    // ---- Phase 2: QKV GEMM. Wave `wid` computes head-wid q,k,v (cols 32*wid of each 256-block) ----
    {
        f32x16 aq[2] = {Z16, Z16}, ak[2] = {Z16, Z16}, av[2] = {Z16, Z16};
        const char* xb = smem;
        const ushort* wrq = wq + (size_t)(      32 * wid + l31) * 256;
        const ushort* wrk = wq + (size_t)(256 + 32 * wid + l31) * 256;
        const ushort* wrv = wq + (size_t)(512 + 32 * wid + l31) * 256;
#pragma unroll 4
        for (int ks = 0; ks < 16; ++ks) {
            const int kk = ks * 16 + kb;
            f16x8 a0 = *(const f16x8*)(xb + ( l31       * XN_ROW + kk) * 2);
            f16x8 a1 = *(const f16x8*)(xb + ((32 + l31) * XN_ROW + kk) * 2);
            f16x8 bq = *(const f16x8*)(wrq + kk);
            f16x8 bk = *(const f16x8*)(wrk + kk);
            f16x8 bv = *(const f16x8*)(wrv + kk);
            aq[0] = MFMA16(a0, bq, aq[0], 0, 0, 0);
            aq[1] = MFMA16(a1, bq, aq[1], 0, 0, 0);
            ak[0] = MFMA16(a0, bk, ak[0], 0, 0, 0);
            ak[1] = MFMA16(a1, bk, ak[1], 0, 0, 0);
            av[0] = MFMA16(a0, bv, av[0], 0, 0, 0);
            av[1] = MFMA16(a1, bv, av[1], 0, 0, 0);
        }
        char* qh = smem + Q_OFF  + wid * QK_HEAD;
        char* kh = smem + K_OFF  + wid * QK_HEAD;
        char* vh = smem + VT_OFF + wid * VT_HEAD;
#pragma unroll
        for (int mt = 0; mt < 2; ++mt) {
#pragma unroll
            for (int r = 0; r < 16; ++r) {      // q,k row-major [p][c]
                const int prow = 32 * mt + (r & 3) + 8 * (r >> 2) + 4 * h5;
                *(ushort*)(qh + (prow * QK_ROW + l31) * 2) = f2h_bits(aq[mt][r]);
                *(ushort*)(kh + (prow * QK_ROW + l31) * 2) = f2h_bits(ak[mt][r]);
            }
#pragma unroll
            for (int sg = 0; sg < 4; ++sg) {    // v transposed [c][kv], packed b64 writes
                const int kvr = 32 * mt + 8 * sg + 4 * h5;
                u32x2 pv2;
                pv2[0] = pk2(av[mt][4*sg+0], av[mt][4*sg+1]);
                pv2[1] = pk2(av[mt][4*sg+2], av[mt][4*sg+3]);
                *(u32x2*)(vh + (l31 * VT_ROW + kvr) * 2) = pv2;
            }
        }
    }
    __syncthreads();

    // ---- Phase 3: attention, one head per wave ----
    {
        const int h = wid;
        const char* qh = smem + Q_OFF  + h * QK_HEAD;
        const char* kh = smem + K_OFF  + h * QK_HEAD;
        const char* vh = smem + VT_OFF + h * VT_HEAD;

        // S^T[kv][qrow] = mfma(A=K, B=Q) : softmax axis (kv) ends up lane-local-ish
        f32x16 st[2][2] = {{Z16, Z16}, {Z16, Z16}};
#pragma unroll
        for (int ks = 0; ks < 2; ++ks) {
            const int cc = ks * 16 + kb;
            f16x8 ka0 = *(const f16x8*)(kh + ( l31       * QK_ROW + cc) * 2);
            f16x8 ka1 = *(const f16x8*)(kh + ((32 + l31) * QK_ROW + cc) * 2);
            f16x8 qb0 = *(const f16x8*)(qh + ( l31       * QK_ROW + cc) * 2);
            f16x8 qb1 = *(const f16x8*)(qh + ((32 + l31) * QK_ROW + cc) * 2);
            st[0][0] = MFMA16(ka0, qb0, st[0][0], 0, 0, 0);
            st[0][1] = MFMA16(ka0, qb1, st[0][1], 0, 0, 0);
            st[1][0] = MFMA16(ka1, qb0, st[1][0], 0, 0, 0);
            st[1][1] = MFMA16(ka1, qb1, st[1][1], 0, 0, 0);
        }
        // + relative position bias (pre-gathered in fragment order)
#pragma unroll
        for (int mt = 0; mt < 2; ++mt)
#pragma unroll
        for (int nt = 0; nt < 2; ++nt) {
            const float* bp = biasr + ((((h * 2 + mt) * 2 + nt) * 64) + lane) * 16;
#pragma unroll
            for (int q4 = 0; q4 < 4; ++q4) {
                f32x4 bv = *(const f32x4*)(bp + 4 * q4);
                st[mt][nt][4*q4+0] += bv[0];
                st[mt][nt][4*q4+1] += bv[1];
                st[mt][nt][4*q4+2] += bv[2];
                st[mt][nt][4*q4+3] += bv[3];
            }
        }
        // softmax over kv: in-lane 32 values + partner half via shfl_xor(32)
#pragma unroll
        for (int nt = 0; nt < 2; ++nt) {
            float mx = st[0][nt][0];
#pragma unroll
            for (int mt = 0; mt < 2; ++mt)
#pragma unroll
            for (int r = 0; r < 16; ++r) mx = fmaxf(mx, st[mt][nt][r]);
            mx = fmaxf(mx, __shfl_xor(mx, 32, 64));
            float sum = 0.f;
#pragma unroll
            for (int mt = 0; mt < 2; ++mt)
#pragma unroll
            for (int r = 0; r < 16; ++r) {
                float e = __expf(st[mt][nt][r] - mx);
                st[mt][nt][r] = e;
                sum += e;
            }
            sum += __shfl_xor(sum, 32, 64);
            const float rd = __builtin_amdgcn_rcpf(sum);
#pragma unroll
            for (int mt = 0; mt < 2; ++mt)
#pragma unroll
            for (int r = 0; r < 16; ++r) st[mt][nt][r] *= rd;
        }
        // pack P to fp16 pair-words: Wd[nt][mt][s][u] covers kv = 32mt+8s+4h5+2u+{0,1}
        uint Wd[2][2][4][2];
#pragma unroll
        for (int nt = 0; nt < 2; ++nt)
#pragma unroll
        for (int mt = 0; mt < 2; ++mt)
#pragma unroll
        for (int sg = 0; sg < 4; ++sg) {
            Wd[nt][mt][sg][0] = pk2(st[mt][nt][4*sg+0], st[mt][nt][4*sg+1]);
            Wd[nt][mt][sg][1] = pk2(st[mt][nt][4*sg+2], st[mt][nt][4*sg+3]);
        }
        // PV: O[qrow][c] = P x V ; A built in-register with one half-exchange per word pair
        f32x16 o[2] = {Z16, Z16};
#pragma unroll
        for (int ks = 0; ks < 4; ++ks) {
            f16x8 bV = *(const f16x8*)(vh + (l31 * VT_ROW + ks * 16 + kb) * 2);
            const int mt = ks >> 1;
            const int sk = 2 * (ks & 1);
#pragma unroll
            for (int nt = 0; nt < 2; ++nt) {
                const uint lo0 = Wd[nt][mt][sk + 0][0], lo1 = Wd[nt][mt][sk + 0][1];
                const uint hi0 = Wd[nt][mt][sk + 1][0], hi1 = Wd[nt][mt][sk + 1][1];
                const uint s0 = h5 ? lo0 : hi0;           // send what partner needs
                const uint s1 = h5 ? lo1 : hi1;
                const uint r0 = (uint)__shfl_xor((int)s0, 32, 64);
                const uint r1 = (uint)__shfl_xor((int)s1, 32, 64);
                union { uint u[4]; f16x8 v; } A;
                A.u[0] = h5 ? r0 : lo0;                   // k = 8*0 + {0..3}
                A.u[1] = h5 ? r1 : lo1;
                A.u[2] = h5 ? hi0 : r0;                   // k = 8*1 + {0..3}
                A.u[3] = h5 ? hi1 : r1;
                o[nt] = MFMA16(A.v, bV, o[nt], 0, 0, 0);
            }
        }
        // write attention output into the (now free) xn region: AO[row][h*32 + c]
        char* ao = smem;
#pragma unroll
        for (int nt = 0; nt < 2; ++nt)
#pragma unroll
        for (int r = 0; r < 16; ++r) {
            const int row = 32 * nt + (r & 3) + 8 * (r >> 2) + 4 * h5;
            *(ushort*)(ao + (row * XN_ROW + h * 32 + l31) * 2) = f2h_bits(o[nt][r]);
        }
    }
    __syncthreads();

    // ---- Phase 4: proj GEMM + bias, write f32 output ----
    {
        const ushort* wr = wp + (size_t)(32 * wid + l31) * 256;
        const char* ao = smem;
        f32x16 pa[2] = {Z16, Z16};
#pragma unroll 4
        for (int ks = 0; ks < 16; ++ks) {
            const int kk = ks * 16 + kb;
            f16x8 a0 = *(const f16x8*)(ao + ( l31       * XN_ROW + kk) * 2);
            f16x8 a1 = *(const f16x8*)(ao + ((32 + l31) * XN_ROW + kk) * 2);
            f16x8 bw = *(const f16x8*)(wr + kk);
            pa[0] = MFMA16(a0, bw, pa[0], 0, 0, 0);
            pa[1] = MFMA16(a1, bw, pa[1], 0, 0, 0);
        }
        const float pb = projb[32 * wid + l31];
        float* orow = out + (size_t)w * 16384;
#pragma unroll
        for (int mt = 0; mt < 2; ++mt)
#pragma unroll
        for (int r = 0; r < 16; ++r) {
            const int prow = 32 * mt + (r & 3) + 8 * (r >> 2) + 4 * h5;
            orow[(size_t)prow * 256 + 32 * wid + l31] = pa[mt][r] + pb;
        }
    }
}

extern "C" void kernel_launch(void* const* d_in, const int* in_sizes, int n_in,
                              void* d_out, int out_size, void* d_ws, size_t ws_size,
                              hipStream_t stream)
{
    const float* x     = (const float*)d_in[0];
    const float* nz    = (const float*)d_in[1];
    const float* gamma = (const float*)d_in[2];
    const float* beta  = (const float*)d_in[3];
    const float* qkvw  = (const float*)d_in[4];
    const float* projw = (const float*)d_in[5];
    const float* projb = (const float*)d_in[6];
    const float* table = (const float*)d_in[7];
    const int*   ridx  = (const int*)d_in[8];

    ushort* wqb   = (ushort*)d_ws;            // 196608 fp16
    ushort* wpb   = wqb + 196608;             // 65536 fp16
    float*  biasr = (float*)(wpb + 65536);    // 32768 f32

    (void)hipFuncSetAttribute((const void*)lwa_main,
                              hipFuncAttributeMaxDynamicSharedMemorySize, LDS_TOTAL);

    lwa_prep<<<1152, 256, 0, stream>>>(qkvw, projw, table, ridx, wqb, wpb, biasr);
    lwa_main<<<2048, 512, LDS_TOTAL, stream>>>(x, nz, gamma, beta, wqb, wpb, biasr, projb,
                                               (float*)d_out);
}